// Round 1
// baseline (379.841 us; speedup 1.0000x reference)
//
#include <hip/hip_runtime.h>
#include <cstdint>

// Problem constants
#define BB 4
#define SS 2048
#define HH 1024
#define NHH 16
#define HDD 64
// M = BB*SS = 8192

typedef __bf16 bf16x8 __attribute__((ext_vector_type(8)));
typedef float f32x4 __attribute__((ext_vector_type(4)));

__device__ __forceinline__ unsigned short f2b(float f) {
    unsigned int u = __float_as_uint(f);
    u += 0x7fffu + ((u >> 16) & 1u);   // round-to-nearest-even
    return (unsigned short)(u >> 16);
}

// ---------------- fp32 -> bf16 conversion ----------------
__global__ void cvt_bf16(const float* __restrict__ in,
                         unsigned short* __restrict__ out, long n) {
    long i = ((long)blockIdx.x * blockDim.x + threadIdx.x) * 4;
    long stride = (long)gridDim.x * blockDim.x * 4;
    for (; i < n; i += stride) {
        float4 v = *reinterpret_cast<const float4*>(in + i);
        ushort4 o;
        o.x = f2b(v.x); o.y = f2b(v.y); o.z = f2b(v.z); o.w = f2b(v.w);
        *reinterpret_cast<ushort4*>(out + i) = o;
    }
}

// ---------------- GEMM: C[m][n] = sum_k A[m][k]*B[n][k] + bias[n] ----------------
// MODE 0: write bf16 C row-major [M][N]
// MODE 1: write bf16 V transposed per head: Vt[((b*NH+head)*HD+d)*S + s]
// MODE 2: write fp32 C row-major [M][N]
template<int MODE>
__global__ __launch_bounds__(256) void gemm_bt(
    const unsigned short* __restrict__ A,   // [M][K] bf16
    const unsigned short* __restrict__ Bm,  // [N][K] bf16
    const float* __restrict__ bias,         // [N]
    void* __restrict__ Cout,
    int M, int N, int K)
{
    __shared__ alignas(16) unsigned short Al[128][40];
    __shared__ alignas(16) unsigned short Bl[128][40];

    const int tid = threadIdx.x;
    const int lane = tid & 63;
    const int wid  = tid >> 6;
    const int wm = wid >> 1, wn = wid & 1;
    const int l15 = lane & 15, g = lane >> 4;
    const int row0 = blockIdx.y * 128, col0 = blockIdx.x * 128;

    f32x4 acc[4][4];
#pragma unroll
    for (int i = 0; i < 4; i++)
#pragma unroll
        for (int j = 0; j < 4; j++) acc[i][j] = (f32x4)0.0f;

    const int sr = tid >> 1;          // 0..127
    const int sc = (tid & 1) * 16;    // 0 or 16

    for (int k0 = 0; k0 < K; k0 += 32) {
        const unsigned short* gA = A  + (size_t)(row0 + sr) * K + k0 + sc;
        const unsigned short* gB = Bm + (size_t)(col0 + sr) * K + k0 + sc;
        *reinterpret_cast<int4*>(&Al[sr][sc])     = *reinterpret_cast<const int4*>(gA);
        *reinterpret_cast<int4*>(&Al[sr][sc + 8]) = *reinterpret_cast<const int4*>(gA + 8);
        *reinterpret_cast<int4*>(&Bl[sr][sc])     = *reinterpret_cast<const int4*>(gB);
        *reinterpret_cast<int4*>(&Bl[sr][sc + 8]) = *reinterpret_cast<const int4*>(gB + 8);
        __syncthreads();

        bf16x8 af[4], bf[4];
#pragma unroll
        for (int i = 0; i < 4; i++)
            af[i] = *reinterpret_cast<const bf16x8*>(&Al[wm * 64 + i * 16 + l15][g * 8]);
#pragma unroll
        for (int j = 0; j < 4; j++)
            bf[j] = *reinterpret_cast<const bf16x8*>(&Bl[wn * 64 + j * 16 + l15][g * 8]);
#pragma unroll
        for (int i = 0; i < 4; i++)
#pragma unroll
            for (int j = 0; j < 4; j++)
                acc[i][j] = __builtin_amdgcn_mfma_f32_16x16x32_bf16(af[i], bf[j], acc[i][j], 0, 0, 0);
        __syncthreads();
    }

    // epilogue
#pragma unroll
    for (int i = 0; i < 4; i++) {
#pragma unroll
        for (int j = 0; j < 4; j++) {
#pragma unroll
            for (int r = 0; r < 4; r++) {
                int row = row0 + wm * 64 + i * 16 + g * 4 + r;
                int col = col0 + wn * 64 + j * 16 + l15;
                float v = acc[i][j][r] + bias[col];
                if (MODE == 0) {
                    reinterpret_cast<unsigned short*>(Cout)[(size_t)row * N + col] = f2b(v);
                } else if (MODE == 1) {
                    int b = row >> 11;          // row / S
                    int s = row & (SS - 1);
                    int head = col >> 6;        // col / HD
                    int d = col & (HDD - 1);
                    size_t idx = (((size_t)b * NHH + head) * HDD + d) * SS + s;
                    reinterpret_cast<unsigned short*>(Cout)[idx] = f2b(v);
                } else {
                    reinterpret_cast<float*>(Cout)[(size_t)row * N + col] = v;
                }
            }
        }
    }
}

// ---------------- Flash attention ----------------
// Q,K: bf16 [B*S][H] (per head: columns h*64..h*64+63)
// Vt:  bf16 [B][NH][HD][S]
// Oa:  bf16 [B*S][H]
__global__ __launch_bounds__(256) void attn_kernel(
    const unsigned short* __restrict__ Q,
    const unsigned short* __restrict__ K,
    const unsigned short* __restrict__ Vt,
    unsigned short* __restrict__ Oa)
{
    __shared__ alignas(16) unsigned short Kl[64][72];
    __shared__ alignas(16) unsigned short Vl[64][72];
    __shared__ alignas(16) unsigned short Pl[4][16][72];

    const int tid = threadIdx.x;
    const int lane = tid & 63;
    const int wid  = tid >> 6;
    const int l15 = lane & 15, g = lane >> 4;

    const int b  = blockIdx.z;
    const int h  = blockIdx.y;
    const int q0 = blockIdx.x * 64;
    const int qrow_base = q0 + wid * 16;

    // Q fragments (held in regs for whole kernel): A-frag rows = l15, k = g*8..+7 (+32)
    const unsigned short* qptr =
        Q + (size_t)(b * SS + qrow_base + l15) * HH + h * HDD + g * 8;
    bf16x8 qf0 = *reinterpret_cast<const bf16x8*>(qptr);
    bf16x8 qf1 = *reinterpret_cast<const bf16x8*>(qptr + 32);

    f32x4 acc_o[4];
#pragma unroll
    for (int dn = 0; dn < 4; dn++) acc_o[dn] = (f32x4)0.0f;
    float m_run[4] = {-INFINITY, -INFINITY, -INFINITY, -INFINITY};
    float l_run[4] = {0.f, 0.f, 0.f, 0.f};

    const int sr = tid >> 2;          // 0..63
    const int sc = (tid & 3) * 16;    // 0,16,32,48

    for (int kt = 0; kt < SS / 64; kt++) {
        // stage K tile [64 keys][64 d] and Vt tile [64 d][64 keys]
        const unsigned short* gK =
            K + (size_t)(b * SS + kt * 64 + sr) * HH + h * HDD + sc;
        const unsigned short* gV =
            Vt + (((size_t)b * NHH + h) * HDD + sr) * SS + kt * 64 + sc;
        *reinterpret_cast<int4*>(&Kl[sr][sc])     = *reinterpret_cast<const int4*>(gK);
        *reinterpret_cast<int4*>(&Kl[sr][sc + 8]) = *reinterpret_cast<const int4*>(gK + 8);
        *reinterpret_cast<int4*>(&Vl[sr][sc])     = *reinterpret_cast<const int4*>(gV);
        *reinterpret_cast<int4*>(&Vl[sr][sc + 8]) = *reinterpret_cast<const int4*>(gV + 8);
        __syncthreads();

        // QK^T: scores[q=16 rows of this wave][64 keys]
        f32x4 sacc[4];
#pragma unroll
        for (int n = 0; n < 4; n++) {
            sacc[n] = (f32x4)0.0f;
            bf16x8 kf0 = *reinterpret_cast<const bf16x8*>(&Kl[n * 16 + l15][g * 8]);
            bf16x8 kf1 = *reinterpret_cast<const bf16x8*>(&Kl[n * 16 + l15][32 + g * 8]);
            sacc[n] = __builtin_amdgcn_mfma_f32_16x16x32_bf16(qf0, kf0, sacc[n], 0, 0, 0);
            sacc[n] = __builtin_amdgcn_mfma_f32_16x16x32_bf16(qf1, kf1, sacc[n], 0, 0, 0);
        }

        // scale + online softmax (rows live on 16-lane groups; regs r = 4 rows)
        float mt[4];
#pragma unroll
        for (int r = 0; r < 4; r++) {
            float m0 = sacc[0][r] * 0.125f; sacc[0][r] = m0;
            float m1 = sacc[1][r] * 0.125f; sacc[1][r] = m1;
            float m2 = sacc[2][r] * 0.125f; sacc[2][r] = m2;
            float m3 = sacc[3][r] * 0.125f; sacc[3][r] = m3;
            mt[r] = fmaxf(fmaxf(m0, m1), fmaxf(m2, m3));
        }
#pragma unroll
        for (int r = 0; r < 4; r++) {
            mt[r] = fmaxf(mt[r], __shfl_xor(mt[r], 1));
            mt[r] = fmaxf(mt[r], __shfl_xor(mt[r], 2));
            mt[r] = fmaxf(mt[r], __shfl_xor(mt[r], 4));
            mt[r] = fmaxf(mt[r], __shfl_xor(mt[r], 8));
        }
        float scl[4], lt[4];
#pragma unroll
        for (int r = 0; r < 4; r++) {
            float mnew = fmaxf(m_run[r], mt[r]);
            scl[r] = __expf(m_run[r] - mnew);
            m_run[r] = mnew;
            float p0 = __expf(sacc[0][r] - mnew);
            float p1 = __expf(sacc[1][r] - mnew);
            float p2 = __expf(sacc[2][r] - mnew);
            float p3 = __expf(sacc[3][r] - mnew);
            sacc[0][r] = p0; sacc[1][r] = p1; sacc[2][r] = p2; sacc[3][r] = p3;
            lt[r] = p0 + p1 + p2 + p3;
        }
#pragma unroll
        for (int r = 0; r < 4; r++) {
            lt[r] += __shfl_xor(lt[r], 1);
            lt[r] += __shfl_xor(lt[r], 2);
            lt[r] += __shfl_xor(lt[r], 4);
            lt[r] += __shfl_xor(lt[r], 8);
            l_run[r] = l_run[r] * scl[r] + lt[r];
        }
#pragma unroll
        for (int dn = 0; dn < 4; dn++)
#pragma unroll
            for (int r = 0; r < 4; r++) acc_o[dn][r] *= scl[r];

        // write P (bf16) to per-wave LDS region: row = q (g*4+r), col = key (n*16+l15)
#pragma unroll
        for (int n = 0; n < 4; n++)
#pragma unroll
            for (int r = 0; r < 4; r++)
                Pl[wid][g * 4 + r][n * 16 + l15] = f2b(sacc[n][r]);

        // PV: O[q][d] += P[q][key] * Vt[d][key]
#pragma unroll
        for (int ks = 0; ks < 2; ks++) {
            bf16x8 pf = *reinterpret_cast<const bf16x8*>(&Pl[wid][l15][ks * 32 + g * 8]);
#pragma unroll
            for (int dn = 0; dn < 4; dn++) {
                bf16x8 vf = *reinterpret_cast<const bf16x8*>(&Vl[dn * 16 + l15][ks * 32 + g * 8]);
                acc_o[dn] = __builtin_amdgcn_mfma_f32_16x16x32_bf16(pf, vf, acc_o[dn], 0, 0, 0);
            }
        }
        __syncthreads();
    }

    // normalize and write O (bf16) to [B*S][H] layout
#pragma unroll
    for (int dn = 0; dn < 4; dn++) {
#pragma unroll
        for (int r = 0; r < 4; r++) {
            int q = qrow_base + g * 4 + r;
            int d = dn * 16 + l15;
            float v = acc_o[dn][r] / l_run[r];
            Oa[(size_t)(b * SS + q) * HH + h * HDD + d] = f2b(v);
        }
    }
}

// ---------------- launcher ----------------
extern "C" void kernel_launch(void* const* d_in, const int* in_sizes, int n_in,
                              void* d_out, int out_size, void* d_ws, size_t ws_size,
                              hipStream_t stream) {
    const float* x  = (const float*)d_in[0];
    const float* Wq = (const float*)d_in[1];
    const float* bq = (const float*)d_in[2];
    const float* Wk = (const float*)d_in[3];
    const float* bk = (const float*)d_in[4];
    const float* Wv = (const float*)d_in[5];
    const float* bv = (const float*)d_in[6];
    const float* Wo = (const float*)d_in[7];
    const float* bo = (const float*)d_in[8];
    float* out = (float*)d_out;

    const int M = BB * SS;   // 8192
    const long nx = (long)M * HH;       // 8388608
    const long nw = (long)HH * HH;      // 1048576

    unsigned char* ws = (unsigned char*)d_ws;
    unsigned short* xb  = (unsigned short*)(ws);
    unsigned short* Wqb = (unsigned short*)(ws + 16777216);
    unsigned short* Wkb = (unsigned short*)(ws + 16777216 + 2097152);
    unsigned short* Wvb = (unsigned short*)(ws + 16777216 + 2 * 2097152);
    unsigned short* Wob = (unsigned short*)(ws + 16777216 + 3 * 2097152);
    unsigned short* Qb  = (unsigned short*)(ws + 16777216 + 4 * 2097152);
    unsigned short* Kb  = (unsigned short*)(ws + 2 * 16777216 + 4 * 2097152);
    unsigned short* Vtb = (unsigned short*)(ws + 3 * 16777216 + 4 * 2097152);
    unsigned short* Ab  = (unsigned short*)(ws + 4 * 16777216 + 4 * 2097152);

    // fp32 -> bf16
    cvt_bf16<<<4096, 256, 0, stream>>>(x, xb, nx);
    cvt_bf16<<<1024, 256, 0, stream>>>(Wq, Wqb, nw);
    cvt_bf16<<<1024, 256, 0, stream>>>(Wk, Wkb, nw);
    cvt_bf16<<<1024, 256, 0, stream>>>(Wv, Wvb, nw);
    cvt_bf16<<<1024, 256, 0, stream>>>(Wo, Wob, nw);

    dim3 ggrid(HH / 128, M / 128);   // (8, 64)
    gemm_bt<0><<<ggrid, 256, 0, stream>>>(xb, Wqb, bq, Qb, M, HH, HH);
    gemm_bt<0><<<ggrid, 256, 0, stream>>>(xb, Wkb, bk, Kb, M, HH, HH);
    gemm_bt<1><<<ggrid, 256, 0, stream>>>(xb, Wvb, bv, Vtb, M, HH, HH);

    dim3 agrid(SS / 64, NHH, BB);    // (32, 16, 4)
    attn_kernel<<<agrid, 256, 0, stream>>>(Qb, Kb, Vtb, Ab);

    gemm_bt<2><<<ggrid, 256, 0, stream>>>(Ab, Wob, bo, out, M, HH, HH);
}

// Round 2
// 348.487 us; speedup vs baseline: 1.0900x; 1.0900x over previous
//
#include <hip/hip_runtime.h>
#include <cstdint>

// Problem constants
#define BB 4
#define SS 2048
#define HH 1024
#define NHH 16
#define HDD 64
// M = BB*SS = 8192

typedef __bf16 bf16x8 __attribute__((ext_vector_type(8)));
typedef float f32x4 __attribute__((ext_vector_type(4)));
typedef unsigned short u16x8 __attribute__((ext_vector_type(8)));

__device__ __forceinline__ unsigned short f2b(float f) {
    unsigned int u = __float_as_uint(f);
    u += 0x7fffu + ((u >> 16) & 1u);   // round-to-nearest-even
    return (unsigned short)(u >> 16);
}

__device__ __forceinline__ void gload_lds16(const void* g, void* l) {
    __builtin_amdgcn_global_load_lds(
        (const __attribute__((address_space(1))) void*)g,
        (__attribute__((address_space(3))) void*)l, 16, 0, 0);
}

// ---------------- fp32 -> bf16 conversion ----------------
__global__ void cvt_bf16(const float* __restrict__ in,
                         unsigned short* __restrict__ out, long n) {
    long i = ((long)blockIdx.x * blockDim.x + threadIdx.x) * 4;
    long stride = (long)gridDim.x * blockDim.x * 4;
    for (; i < n; i += stride) {
        float4 v = *reinterpret_cast<const float4*>(in + i);
        ushort4 o;
        o.x = f2b(v.x); o.y = f2b(v.y); o.z = f2b(v.z); o.w = f2b(v.w);
        *reinterpret_cast<ushort4*>(out + i) = o;
    }
}

// ---------------- GEMM: C[m][n] = sum_k A[m][k]*B[n][k] + bias[n] ----------------
// m97 structure: 128x128 tile, BK=32, global_load_lds width=16, linear LDS.
// MODE 0: write bf16 C row-major [M][N]
// MODE 1: write bf16 V transposed per head with key-permuted seq index:
//         Vt[((b*NH+head)*HD+d)*S + perm(s)], perm within 64: (s&15)*4 + ((s>>4)&3)
// MODE 2: write fp32 C row-major [M][N]
template<int MODE>
__global__ __launch_bounds__(256) void gemm_bt(
    const unsigned short* __restrict__ A,   // [M][K] bf16
    const unsigned short* __restrict__ Bm,  // [N][K] bf16
    const float* __restrict__ bias,         // [N]
    void* __restrict__ Cout,
    int M, int N, int K)
{
    __shared__ alignas(16) unsigned short Al[128][32];
    __shared__ alignas(16) unsigned short Bl[128][32];

    const int tid = threadIdx.x;
    const int lane = tid & 63;
    const int wid  = tid >> 6;
    const int wm = wid >> 1, wn = wid & 1;
    const int l15 = lane & 15, g = lane >> 4;
    const int row0 = blockIdx.y * 128, col0 = blockIdx.x * 128;

    f32x4 acc[4][4];
#pragma unroll
    for (int i = 0; i < 4; i++)
#pragma unroll
        for (int j = 0; j < 4; j++) acc[i][j] = (f32x4)0.0f;

    // staging geometry: linear byte offset off = tid*16 + p*4096 within 8KB tile
    // row = off>>6 (64B per row of 32 bf16), colbyte = off&63
    const int off0 = tid * 16;
    const int r0s = off0 >> 6, cb0 = off0 & 63;
    const int off1 = off0 + 4096;
    const int r1s = off1 >> 6, cb1 = off1 & 63;

    for (int k0 = 0; k0 < K; k0 += 32) {
        const char* gA = (const char*)(A + (size_t)row0 * K + k0);
        const char* gB = (const char*)(Bm + (size_t)col0 * K + k0);
        char* lA = (char*)&Al[0][0] + wid * 1024;
        char* lB = (char*)&Bl[0][0] + wid * 1024;
        gload_lds16(gA + (size_t)r0s * (K * 2) + cb0, lA);
        gload_lds16(gA + (size_t)r1s * (K * 2) + cb1, lA + 4096);
        gload_lds16(gB + (size_t)r0s * (K * 2) + cb0, lB);
        gload_lds16(gB + (size_t)r1s * (K * 2) + cb1, lB + 4096);
        __syncthreads();

        bf16x8 af[4], bf[4];
#pragma unroll
        for (int i = 0; i < 4; i++)
            af[i] = *reinterpret_cast<const bf16x8*>(&Al[wm * 64 + i * 16 + l15][g * 8]);
#pragma unroll
        for (int j = 0; j < 4; j++)
            bf[j] = *reinterpret_cast<const bf16x8*>(&Bl[wn * 64 + j * 16 + l15][g * 8]);
        __builtin_amdgcn_s_setprio(1);
#pragma unroll
        for (int i = 0; i < 4; i++)
#pragma unroll
            for (int j = 0; j < 4; j++)
                acc[i][j] = __builtin_amdgcn_mfma_f32_16x16x32_bf16(af[i], bf[j], acc[i][j], 0, 0, 0);
        __builtin_amdgcn_s_setprio(0);
        __syncthreads();
    }

    // epilogue
#pragma unroll
    for (int i = 0; i < 4; i++) {
#pragma unroll
        for (int j = 0; j < 4; j++) {
#pragma unroll
            for (int r = 0; r < 4; r++) {
                int row = row0 + wm * 64 + i * 16 + g * 4 + r;
                int col = col0 + wn * 64 + j * 16 + l15;
                float v = acc[i][j][r] + bias[col];
                if (MODE == 0) {
                    reinterpret_cast<unsigned short*>(Cout)[(size_t)row * N + col] = f2b(v);
                } else if (MODE == 1) {
                    int b = row >> 11;          // row / S
                    int s = row & (SS - 1);
                    int sp = (s & ~63) | (((s & 15) << 2) | ((s >> 4) & 3));
                    int head = col >> 6;        // col / HD
                    int d = col & (HDD - 1);
                    size_t idx = (((size_t)b * NHH + head) * HDD + d) * SS + sp;
                    reinterpret_cast<unsigned short*>(Cout)[idx] = f2b(v);
                } else {
                    reinterpret_cast<float*>(Cout)[(size_t)row * N + col] = v;
                }
            }
        }
    }
}

// ---------------- Flash attention ----------------
// Q,K: bf16 [B*S][H] (per head: columns h*64..h*64+63)
// Vt:  bf16 [B][NH][HD][S] with seq index key-permuted within each 64-block
// Oa:  bf16 [B*S][H]
__global__ __launch_bounds__(256) void attn_kernel(
    const unsigned short* __restrict__ Q,
    const unsigned short* __restrict__ K,
    const unsigned short* __restrict__ Vt,
    unsigned short* __restrict__ Oa)
{
    __shared__ alignas(16) unsigned short Kl[64][72];
    __shared__ alignas(16) unsigned short Vl[64][72];
    __shared__ alignas(16) unsigned short Pl[4][16][72];

    const int tid = threadIdx.x;
    const int lane = tid & 63;
    const int wid  = tid >> 6;
    const int l15 = lane & 15, g = lane >> 4;

    const int b  = blockIdx.z;
    const int h  = blockIdx.y;
    const int q0 = blockIdx.x * 64;
    const int qrow_base = q0 + wid * 16;

    // Q fragments, prescaled by 1/sqrt(HD) * log2(e) so scores are in log2 domain
    const float qs = 0.125f * 1.44269504088896f;
    const unsigned short* qptr =
        Q + (size_t)(b * SS + qrow_base + l15) * HH + h * HDD + g * 8;
    u16x8 qr0 = *reinterpret_cast<const u16x8*>(qptr);
    u16x8 qr1 = *reinterpret_cast<const u16x8*>(qptr + 32);
#pragma unroll
    for (int j = 0; j < 8; j++) {
        qr0[j] = f2b(__uint_as_float((unsigned)qr0[j] << 16) * qs);
        qr1[j] = f2b(__uint_as_float((unsigned)qr1[j] << 16) * qs);
    }
    bf16x8 qf0 = __builtin_bit_cast(bf16x8, qr0);
    bf16x8 qf1 = __builtin_bit_cast(bf16x8, qr1);

    f32x4 acc_o[4];
#pragma unroll
    for (int dn = 0; dn < 4; dn++) acc_o[dn] = (f32x4)0.0f;
    float m_run[4] = {-INFINITY, -INFINITY, -INFINITY, -INFINITY};
    float l_run[4] = {0.f, 0.f, 0.f, 0.f};

    const int sr = tid >> 2;          // 0..63
    const int sc = (tid & 3) * 16;    // 0,16,32,48

    const unsigned short* Kb = K + (size_t)b * SS * HH + h * HDD;
    const unsigned short* Vb = Vt + (((size_t)b * NHH + h) * HDD) * SS;

    int4 kr0, kr1, vr0, vr1;
    auto load_tile = [&](int kt) {
        const unsigned short* gK = Kb + (size_t)(kt * 64 + sr) * HH + sc;
        const unsigned short* gV = Vb + (size_t)sr * SS + kt * 64 + sc;
        kr0 = *reinterpret_cast<const int4*>(gK);
        kr1 = *reinterpret_cast<const int4*>(gK + 8);
        vr0 = *reinterpret_cast<const int4*>(gV);
        vr1 = *reinterpret_cast<const int4*>(gV + 8);
    };
    auto write_tile = [&]() {
        *reinterpret_cast<int4*>(&Kl[sr][sc])     = kr0;
        *reinterpret_cast<int4*>(&Kl[sr][sc + 8]) = kr1;
        *reinterpret_cast<int4*>(&Vl[sr][sc])     = vr0;
        *reinterpret_cast<int4*>(&Vl[sr][sc + 8]) = vr1;
    };

    const int NT = SS / 64;
    load_tile(0);
    write_tile();
    __syncthreads();

    for (int kt = 0; kt < NT; kt++) {
        // issue next tile's global loads (in flight across this tile's compute)
        if (kt + 1 < NT) load_tile(kt + 1);

        // QK^T: scores[q=16 rows of this wave][64 keys] (log2 domain, prescaled)
        f32x4 sacc[4];
        __builtin_amdgcn_s_setprio(1);
#pragma unroll
        for (int n = 0; n < 4; n++) {
            sacc[n] = (f32x4)0.0f;
            bf16x8 kf0 = *reinterpret_cast<const bf16x8*>(&Kl[n * 16 + l15][g * 8]);
            bf16x8 kf1 = *reinterpret_cast<const bf16x8*>(&Kl[n * 16 + l15][32 + g * 8]);
            sacc[n] = __builtin_amdgcn_mfma_f32_16x16x32_bf16(qf0, kf0, sacc[n], 0, 0, 0);
            sacc[n] = __builtin_amdgcn_mfma_f32_16x16x32_bf16(qf1, kf1, sacc[n], 0, 0, 0);
        }
        __builtin_amdgcn_s_setprio(0);

        // online softmax in log2 domain (rows live on 16-lane groups)
        float mt[4];
#pragma unroll
        for (int r = 0; r < 4; r++)
            mt[r] = fmaxf(fmaxf(sacc[0][r], sacc[1][r]), fmaxf(sacc[2][r], sacc[3][r]));
#pragma unroll
        for (int r = 0; r < 4; r++) {
            mt[r] = fmaxf(mt[r], __shfl_xor(mt[r], 1));
            mt[r] = fmaxf(mt[r], __shfl_xor(mt[r], 2));
            mt[r] = fmaxf(mt[r], __shfl_xor(mt[r], 4));
            mt[r] = fmaxf(mt[r], __shfl_xor(mt[r], 8));
        }
        float scl[4], lt[4];
#pragma unroll
        for (int r = 0; r < 4; r++) {
            float mnew = fmaxf(m_run[r], mt[r]);
            scl[r] = exp2f(m_run[r] - mnew);
            m_run[r] = mnew;
            float p0 = exp2f(sacc[0][r] - mnew);
            float p1 = exp2f(sacc[1][r] - mnew);
            float p2 = exp2f(sacc[2][r] - mnew);
            float p3 = exp2f(sacc[3][r] - mnew);
            sacc[0][r] = p0; sacc[1][r] = p1; sacc[2][r] = p2; sacc[3][r] = p3;
            lt[r] = (p0 + p1) + (p2 + p3);
        }
#pragma unroll
        for (int r = 0; r < 4; r++) {
            lt[r] += __shfl_xor(lt[r], 1);
            lt[r] += __shfl_xor(lt[r], 2);
            lt[r] += __shfl_xor(lt[r], 4);
            lt[r] += __shfl_xor(lt[r], 8);
            l_run[r] = l_run[r] * scl[r] + lt[r];
        }
#pragma unroll
        for (int dn = 0; dn < 4; dn++)
#pragma unroll
            for (int r = 0; r < 4; r++) acc_o[dn][r] *= scl[r];

        // write P (bf16) packed: keys {n*16+l15, n=0..3} -> permuted cols l15*4..+3
#pragma unroll
        for (int r = 0; r < 4; r++) {
            ushort4 pw;
            pw.x = f2b(sacc[0][r]); pw.y = f2b(sacc[1][r]);
            pw.z = f2b(sacc[2][r]); pw.w = f2b(sacc[3][r]);
            *reinterpret_cast<ushort4*>(&Pl[wid][g * 4 + r][l15 * 4]) = pw;
        }

        // PV: O[q][d] += P[q][pk] * V[pk][d]  (pk = permuted key, matches Vt layout)
        __builtin_amdgcn_s_setprio(1);
#pragma unroll
        for (int ks = 0; ks < 2; ks++) {
            bf16x8 pf = *reinterpret_cast<const bf16x8*>(&Pl[wid][l15][ks * 32 + g * 8]);
#pragma unroll
            for (int dn = 0; dn < 4; dn++) {
                bf16x8 vf = *reinterpret_cast<const bf16x8*>(&Vl[dn * 16 + l15][ks * 32 + g * 8]);
                acc_o[dn] = __builtin_amdgcn_mfma_f32_16x16x32_bf16(pf, vf, acc_o[dn], 0, 0, 0);
            }
        }
        __builtin_amdgcn_s_setprio(0);

        __syncthreads();                    // all waves done reading tile kt
        if (kt + 1 < NT) write_tile();      // store next tile (waits on globals)
        __syncthreads();                    // tile kt+1 visible
    }

    // normalize and write O (bf16) to [B*S][H] layout
#pragma unroll
    for (int dn = 0; dn < 4; dn++) {
#pragma unroll
        for (int r = 0; r < 4; r++) {
            int q = qrow_base + g * 4 + r;
            int d = dn * 16 + l15;
            float v = acc_o[dn][r] / l_run[r];
            Oa[(size_t)(b * SS + q) * HH + h * HDD + d] = f2b(v);
        }
    }
}

// ---------------- launcher ----------------
extern "C" void kernel_launch(void* const* d_in, const int* in_sizes, int n_in,
                              void* d_out, int out_size, void* d_ws, size_t ws_size,
                              hipStream_t stream) {
    const float* x  = (const float*)d_in[0];
    const float* Wq = (const float*)d_in[1];
    const float* bq = (const float*)d_in[2];
    const float* Wk = (const float*)d_in[3];
    const float* bk = (const float*)d_in[4];
    const float* Wv = (const float*)d_in[5];
    const float* bv = (const float*)d_in[6];
    const float* Wo = (const float*)d_in[7];
    const float* bo = (const float*)d_in[8];
    float* out = (float*)d_out;

    const int M = BB * SS;   // 8192
    const long nx = (long)M * HH;       // 8388608
    const long nw = (long)HH * HH;      // 1048576

    unsigned char* ws = (unsigned char*)d_ws;
    unsigned short* xb  = (unsigned short*)(ws);
    unsigned short* Wqb = (unsigned short*)(ws + 16777216);
    unsigned short* Wkb = (unsigned short*)(ws + 16777216 + 2097152);
    unsigned short* Wvb = (unsigned short*)(ws + 16777216 + 2 * 2097152);
    unsigned short* Wob = (unsigned short*)(ws + 16777216 + 3 * 2097152);
    unsigned short* Qb  = (unsigned short*)(ws + 16777216 + 4 * 2097152);
    unsigned short* Kb  = (unsigned short*)(ws + 2 * 16777216 + 4 * 2097152);
    unsigned short* Vtb = (unsigned short*)(ws + 3 * 16777216 + 4 * 2097152);
    unsigned short* Ab  = (unsigned short*)(ws + 4 * 16777216 + 4 * 2097152);

    // fp32 -> bf16
    cvt_bf16<<<4096, 256, 0, stream>>>(x, xb, nx);
    cvt_bf16<<<1024, 256, 0, stream>>>(Wq, Wqb, nw);
    cvt_bf16<<<1024, 256, 0, stream>>>(Wk, Wkb, nw);
    cvt_bf16<<<1024, 256, 0, stream>>>(Wv, Wvb, nw);
    cvt_bf16<<<1024, 256, 0, stream>>>(Wo, Wob, nw);

    dim3 ggrid(HH / 128, M / 128);   // (8, 64)
    gemm_bt<0><<<ggrid, 256, 0, stream>>>(xb, Wqb, bq, Qb, M, HH, HH);
    gemm_bt<0><<<ggrid, 256, 0, stream>>>(xb, Wkb, bk, Kb, M, HH, HH);
    gemm_bt<1><<<ggrid, 256, 0, stream>>>(xb, Wvb, bv, Vtb, M, HH, HH);

    dim3 agrid(SS / 64, NHH, BB);    // (32, 16, 4)
    attn_kernel<<<agrid, 256, 0, stream>>>(Qb, Kb, Vtb, Ab);

    gemm_bt<2><<<ggrid, 256, 0, stream>>>(Ab, Wob, bo, out, M, HH, HH);
}

// Round 3
// 275.971 us; speedup vs baseline: 1.3764x; 1.2628x over previous
//
#include <hip/hip_runtime.h>
#include <cstdint>

// Problem constants
#define BB 4
#define SS 2048
#define HH 1024
#define NHH 16
#define HDD 64
// M = BB*SS = 8192

typedef __bf16 bf16x8 __attribute__((ext_vector_type(8)));
typedef float f32x4 __attribute__((ext_vector_type(4)));
typedef unsigned short u16x8 __attribute__((ext_vector_type(8)));

__device__ __forceinline__ unsigned short f2b(float f) {
    unsigned int u = __float_as_uint(f);
    u += 0x7fffu + ((u >> 16) & 1u);   // round-to-nearest-even
    return (unsigned short)(u >> 16);
}

__device__ __forceinline__ void gload_lds16(const void* g, void* l) {
    __builtin_amdgcn_global_load_lds(
        (const __attribute__((address_space(1))) void*)g,
        (__attribute__((address_space(3))) void*)l, 16, 0, 0);
}

// ---------------- fp32 -> bf16 conversion ----------------
__global__ void cvt_bf16(const float* __restrict__ in,
                         unsigned short* __restrict__ out, long n) {
    long i = ((long)blockIdx.x * blockDim.x + threadIdx.x) * 4;
    long stride = (long)gridDim.x * blockDim.x * 4;
    for (; i < n; i += stride) {
        float4 v = *reinterpret_cast<const float4*>(in + i);
        ushort4 o;
        o.x = f2b(v.x); o.y = f2b(v.y); o.z = f2b(v.z); o.w = f2b(v.w);
        *reinterpret_cast<ushort4*>(out + i) = o;
    }
}

// 4 weight matrices (each HH*HH), outputs contiguous at out + y*HH*HH
__global__ void cvt_w4(const float* __restrict__ w0, const float* __restrict__ w1,
                       const float* __restrict__ w2, const float* __restrict__ w3,
                       unsigned short* __restrict__ out) {
    const float* s = blockIdx.y == 0 ? w0 : blockIdx.y == 1 ? w1 : blockIdx.y == 2 ? w2 : w3;
    unsigned short* o = out + (size_t)blockIdx.y * ((size_t)HH * HH);
    long n = (long)HH * HH;
    long stride = (long)gridDim.x * blockDim.x * 4;
    for (long i = ((long)blockIdx.x * blockDim.x + threadIdx.x) * 4; i < n; i += stride) {
        float4 v = *reinterpret_cast<const float4*>(s + i);
        ushort4 w;
        w.x = f2b(v.x); w.y = f2b(v.y); w.z = f2b(v.z); w.w = f2b(v.w);
        *reinterpret_cast<ushort4*>(o + i) = w;
    }
}

// ---------------- GEMM: C[m][n] = sum_k A[m][k]*B[n][k] + bias[n] ----------------
// m97 structure: 128x128 tile, BK=32, global_load_lds width=16, linear LDS.
// MODE 0: write bf16 C row-major [M][N]
// MODE 1: write bf16 V transposed per head with key-permuted seq index
//         (perm within 64: bit perm b4->b2, b3:2->b4:3, so each attn lane's
//          P-fragment is its own PV B-operand)
// MODE 2: write fp32 C row-major [M][N]
template<int MODE>
__global__ __launch_bounds__(256) void gemm_bt(
    const unsigned short* __restrict__ A,   // [M][K] bf16
    const unsigned short* __restrict__ Bm,  // [N][K] bf16
    const float* __restrict__ bias,         // [N]
    void* __restrict__ Cout,
    int M, int N, int K)
{
    __shared__ alignas(16) unsigned short Al[128][32];
    __shared__ alignas(16) unsigned short Bl[128][32];

    const int tid = threadIdx.x;
    const int lane = tid & 63;
    const int wid  = tid >> 6;
    const int wm = wid >> 1, wn = wid & 1;
    const int l15 = lane & 15, g = lane >> 4;
    const int row0 = blockIdx.y * 128, col0 = blockIdx.x * 128;

    f32x4 acc[4][4];
#pragma unroll
    for (int i = 0; i < 4; i++)
#pragma unroll
        for (int j = 0; j < 4; j++) acc[i][j] = (f32x4)0.0f;

    const int off0 = tid * 16;
    const int r0s = off0 >> 6, cb0 = off0 & 63;
    const int off1 = off0 + 4096;
    const int r1s = off1 >> 6, cb1 = off1 & 63;

    for (int k0 = 0; k0 < K; k0 += 32) {
        const char* gA = (const char*)(A + (size_t)row0 * K + k0);
        const char* gB = (const char*)(Bm + (size_t)col0 * K + k0);
        char* lA = (char*)&Al[0][0] + wid * 1024;
        char* lB = (char*)&Bl[0][0] + wid * 1024;
        gload_lds16(gA + (size_t)r0s * (K * 2) + cb0, lA);
        gload_lds16(gA + (size_t)r1s * (K * 2) + cb1, lA + 4096);
        gload_lds16(gB + (size_t)r0s * (K * 2) + cb0, lB);
        gload_lds16(gB + (size_t)r1s * (K * 2) + cb1, lB + 4096);
        __syncthreads();

        bf16x8 af[4], bf[4];
#pragma unroll
        for (int i = 0; i < 4; i++)
            af[i] = *reinterpret_cast<const bf16x8*>(&Al[wm * 64 + i * 16 + l15][g * 8]);
#pragma unroll
        for (int j = 0; j < 4; j++)
            bf[j] = *reinterpret_cast<const bf16x8*>(&Bl[wn * 64 + j * 16 + l15][g * 8]);
        __builtin_amdgcn_s_setprio(1);
#pragma unroll
        for (int i = 0; i < 4; i++)
#pragma unroll
            for (int j = 0; j < 4; j++)
                acc[i][j] = __builtin_amdgcn_mfma_f32_16x16x32_bf16(af[i], bf[j], acc[i][j], 0, 0, 0);
        __builtin_amdgcn_s_setprio(0);
        __syncthreads();
    }

    // epilogue
#pragma unroll
    for (int i = 0; i < 4; i++) {
#pragma unroll
        for (int j = 0; j < 4; j++) {
#pragma unroll
            for (int r = 0; r < 4; r++) {
                int row = row0 + wm * 64 + i * 16 + g * 4 + r;
                int col = col0 + wn * 64 + j * 16 + l15;
                float v = acc[i][j][r] + bias[col];
                if (MODE == 0) {
                    reinterpret_cast<unsigned short*>(Cout)[(size_t)row * N + col] = f2b(v);
                } else if (MODE == 1) {
                    int b = row >> 11;          // row / S
                    int s = row & (SS - 1);
                    int s6 = s & 63;
                    int sp6 = (s6 & 0x23) | ((s6 & 0x0C) << 1) | ((s6 & 0x10) >> 2);
                    int head = col >> 6;        // col / HD
                    int d = col & (HDD - 1);
                    size_t idx = (((size_t)b * NHH + head) * HDD + d) * SS + (s & ~63) + sp6;
                    reinterpret_cast<unsigned short*>(Cout)[idx] = f2b(v);
                } else {
                    reinterpret_cast<float*>(Cout)[(size_t)row * N + col] = v;
                }
            }
        }
    }
}

// ---------------- Flash attention (swapped QK^T, P stays in registers) ----------------
// Q,K: bf16 [B*S][H] (per head: columns h*64..h*64+63)
// Vt:  bf16 [B][NH][HD][S], seq index key-permuted within each 64-block
// Oa:  bf16 [B*S][H]
__global__ __launch_bounds__(256) void attn_kernel(
    const unsigned short* __restrict__ Q,
    const unsigned short* __restrict__ K,
    const unsigned short* __restrict__ Vt,
    unsigned short* __restrict__ Oa)
{
    __shared__ alignas(16) unsigned short Kl[64][72];
    __shared__ alignas(16) unsigned short Vl[64][72];

    const int tid = threadIdx.x;
    const int lane = tid & 63;
    const int wid  = tid >> 6;
    const int l15 = lane & 15, g = lane >> 4;

    const int b  = blockIdx.z;
    const int h  = blockIdx.y;
    const int q0 = blockIdx.x * 128;
    const int qA = q0 + wid * 32;       // this wave: q-cols qA..qA+15 (block A), +16..31 (block B)

    // Q as B-fragments: lane holds Q[q = l15][d = g*8 + j], prescaled into log2 domain
    const float qs = 0.125f * 1.44269504088896f;
    const unsigned short* qpA = Q + (size_t)(b * SS + qA + l15) * HH + h * HDD + g * 8;
    const unsigned short* qpB = qpA + (size_t)16 * HH;
    u16x8 ra0 = *reinterpret_cast<const u16x8*>(qpA);
    u16x8 ra1 = *reinterpret_cast<const u16x8*>(qpA + 32);
    u16x8 rb0 = *reinterpret_cast<const u16x8*>(qpB);
    u16x8 rb1 = *reinterpret_cast<const u16x8*>(qpB + 32);
#pragma unroll
    for (int j = 0; j < 8; j++) {
        ra0[j] = f2b(__uint_as_float((unsigned)ra0[j] << 16) * qs);
        ra1[j] = f2b(__uint_as_float((unsigned)ra1[j] << 16) * qs);
        rb0[j] = f2b(__uint_as_float((unsigned)rb0[j] << 16) * qs);
        rb1[j] = f2b(__uint_as_float((unsigned)rb1[j] << 16) * qs);
    }
    bf16x8 qa0 = __builtin_bit_cast(bf16x8, ra0);
    bf16x8 qa1 = __builtin_bit_cast(bf16x8, ra1);
    bf16x8 qb0 = __builtin_bit_cast(bf16x8, rb0);
    bf16x8 qb1 = __builtin_bit_cast(bf16x8, rb1);

    u16x8 ou; 
#pragma unroll
    for (int j = 0; j < 8; j++) ou[j] = 0x3F80;   // bf16 1.0
    const bf16x8 ones8 = __builtin_bit_cast(bf16x8, ou);
    const f32x4 zero4 = (f32x4)0.0f;

    f32x4 acc_a[4], acc_b[4];
#pragma unroll
    for (int dn = 0; dn < 4; dn++) { acc_a[dn] = zero4; acc_b[dn] = zero4; }
    float m_a = -INFINITY, m_b = -INFINITY, l_a = 0.f, l_b = 0.f;

    const int sr = tid >> 2;          // 0..63
    const int sc = (tid & 3) * 16;    // 0,16,32,48

    const unsigned short* Kbp = K + (size_t)b * SS * HH + h * HDD;
    const unsigned short* Vbp = Vt + ((size_t)b * NHH + h) * HDD * SS;

    int4 kr0, kr1, vr0, vr1;
    auto load_tile = [&](int kt) {
        const unsigned short* gK = Kbp + (size_t)(kt * 64 + sr) * HH + sc;
        const unsigned short* gV = Vbp + (size_t)sr * SS + kt * 64 + sc;
        kr0 = *reinterpret_cast<const int4*>(gK);
        kr1 = *reinterpret_cast<const int4*>(gK + 8);
        vr0 = *reinterpret_cast<const int4*>(gV);
        vr1 = *reinterpret_cast<const int4*>(gV + 8);
    };
    auto write_tile = [&]() {
        *reinterpret_cast<int4*>(&Kl[sr][sc])     = kr0;
        *reinterpret_cast<int4*>(&Kl[sr][sc + 8]) = kr1;
        *reinterpret_cast<int4*>(&Vl[sr][sc])     = vr0;
        *reinterpret_cast<int4*>(&Vl[sr][sc + 8]) = vr1;
    };

    // softmax for one 16-q block; P emitted directly as PV B-fragments
    auto softmax = [&](f32x4 (&s)[4], float& m, float& l, f32x4 (&ao)[4],
                       bf16x8& p0, bf16x8& p1) {
        float u0 = fmaxf(fmaxf(s[0][0], s[0][1]), fmaxf(s[0][2], s[0][3]));
        float u1 = fmaxf(fmaxf(s[1][0], s[1][1]), fmaxf(s[1][2], s[1][3]));
        float u2 = fmaxf(fmaxf(s[2][0], s[2][1]), fmaxf(s[2][2], s[2][3]));
        float u3 = fmaxf(fmaxf(s[3][0], s[3][1]), fmaxf(s[3][2], s[3][3]));
        float mt = fmaxf(fmaxf(u0, u1), fmaxf(u2, u3));
        mt = fmaxf(mt, __shfl_xor(mt, 16));
        mt = fmaxf(mt, __shfl_xor(mt, 32));
        if (!__all(mt - m <= 8.0f)) {       // defer-max: rescale only on real growth
            float mnew = fmaxf(m, mt);
            float scl = exp2f(m - mnew);
            m = mnew;
            l *= scl;
#pragma unroll
            for (int dn = 0; dn < 4; dn++)
#pragma unroll
                for (int r = 0; r < 4; r++) ao[dn][r] *= scl;
        }
        float p[4][4];
#pragma unroll
        for (int n = 0; n < 4; n++)
#pragma unroll
            for (int r = 0; r < 4; r++) p[n][r] = exp2f(s[n][r] - m);
#pragma unroll
        for (int j = 0; j < 8; j++) {
            p0[j] = (__bf16)p[j >> 2][j & 3];
            p1[j] = (__bf16)p[2 + (j >> 2)][j & 3];
        }
    };

    const int NT = SS / 64;
    load_tile(0);
    write_tile();
    __syncthreads();

    for (int kt = 0; kt < NT; kt++) {
        if (kt + 1 < NT) load_tile(kt + 1);   // in flight across this tile's compute

        // QK^T swapped: C[key][q].  A = K-frag (LDS), B = Q-frag (regs).
        f32x4 sa[4], sb[4];
        __builtin_amdgcn_s_setprio(1);
#pragma unroll
        for (int n = 0; n < 4; n++) {
            bf16x8 kf0 = *reinterpret_cast<const bf16x8*>(&Kl[n * 16 + l15][g * 8]);
            bf16x8 kf1 = *reinterpret_cast<const bf16x8*>(&Kl[n * 16 + l15][32 + g * 8]);
            sa[n] = __builtin_amdgcn_mfma_f32_16x16x32_bf16(kf0, qa0, zero4, 0, 0, 0);
            sa[n] = __builtin_amdgcn_mfma_f32_16x16x32_bf16(kf1, qa1, sa[n], 0, 0, 0);
            sb[n] = __builtin_amdgcn_mfma_f32_16x16x32_bf16(kf0, qb0, zero4, 0, 0, 0);
            sb[n] = __builtin_amdgcn_mfma_f32_16x16x32_bf16(kf1, qb1, sb[n], 0, 0, 0);
        }
        __builtin_amdgcn_s_setprio(0);

        bf16x8 pa0, pa1, pb0, pb1;
        softmax(sa, m_a, l_a, acc_a, pa0, pa1);
        softmax(sb, m_b, l_b, acc_b, pb0, pb1);

        // PV (O^T): A = Vt-frag (LDS, permuted keys), B = P (lane-local regs).
        // l-sums ride the MFMA pipe via a ones-A-fragment.
        f32x4 la = zero4, lb = zero4;
        __builtin_amdgcn_s_setprio(1);
#pragma unroll
        for (int ks = 0; ks < 2; ks++) {
            bf16x8 pA = ks ? pa1 : pa0;
            bf16x8 pB = ks ? pb1 : pb0;
#pragma unroll
            for (int dn = 0; dn < 4; dn++) {
                bf16x8 vf = *reinterpret_cast<const bf16x8*>(&Vl[dn * 16 + l15][ks * 32 + g * 8]);
                acc_a[dn] = __builtin_amdgcn_mfma_f32_16x16x32_bf16(vf, pA, acc_a[dn], 0, 0, 0);
                acc_b[dn] = __builtin_amdgcn_mfma_f32_16x16x32_bf16(vf, pB, acc_b[dn], 0, 0, 0);
            }
        }
        la = __builtin_amdgcn_mfma_f32_16x16x32_bf16(ones8, pa0, la, 0, 0, 0);
        la = __builtin_amdgcn_mfma_f32_16x16x32_bf16(ones8, pa1, la, 0, 0, 0);
        lb = __builtin_amdgcn_mfma_f32_16x16x32_bf16(ones8, pb0, lb, 0, 0, 0);
        lb = __builtin_amdgcn_mfma_f32_16x16x32_bf16(ones8, pb1, lb, 0, 0, 0);
        __builtin_amdgcn_s_setprio(0);
        l_a += la[0];
        l_b += lb[0];

        __syncthreads();                    // all waves done reading tile kt
        if (kt + 1 < NT) write_tile();      // store next tile (waits on globals)
        __syncthreads();                    // tile kt+1 visible
    }

    // normalize and write O: lane holds O[q = l15][d = dn*16 + g*4 + r]
    float inv_a = 1.0f / l_a;
    float inv_b = 1.0f / l_b;
    unsigned short* oA = Oa + (size_t)(b * SS + qA + l15) * HH + h * HDD;
    unsigned short* oB = oA + (size_t)16 * HH;
#pragma unroll
    for (int dn = 0; dn < 4; dn++) {
        ushort4 wa, wb;
        wa.x = f2b(acc_a[dn][0] * inv_a); wa.y = f2b(acc_a[dn][1] * inv_a);
        wa.z = f2b(acc_a[dn][2] * inv_a); wa.w = f2b(acc_a[dn][3] * inv_a);
        wb.x = f2b(acc_b[dn][0] * inv_b); wb.y = f2b(acc_b[dn][1] * inv_b);
        wb.z = f2b(acc_b[dn][2] * inv_b); wb.w = f2b(acc_b[dn][3] * inv_b);
        *reinterpret_cast<ushort4*>(oA + dn * 16 + g * 4) = wa;
        *reinterpret_cast<ushort4*>(oB + dn * 16 + g * 4) = wb;
    }
}

// ---------------- launcher ----------------
extern "C" void kernel_launch(void* const* d_in, const int* in_sizes, int n_in,
                              void* d_out, int out_size, void* d_ws, size_t ws_size,
                              hipStream_t stream) {
    const float* x  = (const float*)d_in[0];
    const float* Wq = (const float*)d_in[1];
    const float* bq = (const float*)d_in[2];
    const float* Wk = (const float*)d_in[3];
    const float* bk = (const float*)d_in[4];
    const float* Wv = (const float*)d_in[5];
    const float* bv = (const float*)d_in[6];
    const float* Wo = (const float*)d_in[7];
    const float* bo = (const float*)d_in[8];
    float* out = (float*)d_out;

    const int M = BB * SS;   // 8192
    const long nx = (long)M * HH;       // 8388608

    unsigned char* ws = (unsigned char*)d_ws;
    unsigned short* xb  = (unsigned short*)(ws);
    unsigned short* Wqb = (unsigned short*)(ws + 16777216);
    unsigned short* Wkb = (unsigned short*)(ws + 16777216 + 2097152);
    unsigned short* Wvb = (unsigned short*)(ws + 16777216 + 2 * 2097152);
    unsigned short* Wob = (unsigned short*)(ws + 16777216 + 3 * 2097152);
    unsigned short* Qb  = (unsigned short*)(ws + 16777216 + 4 * 2097152);
    unsigned short* Kb  = (unsigned short*)(ws + 2 * 16777216 + 4 * 2097152);
    unsigned short* Vtb = (unsigned short*)(ws + 3 * 16777216 + 4 * 2097152);
    unsigned short* Ab  = (unsigned short*)(ws + 4 * 16777216 + 4 * 2097152);

    // fp32 -> bf16
    cvt_bf16<<<4096, 256, 0, stream>>>(x, xb, nx);
    cvt_w4<<<dim3(256, 4), 256, 0, stream>>>(Wq, Wk, Wv, Wo, Wqb);

    dim3 ggrid(HH / 128, M / 128);   // (8, 64)
    gemm_bt<0><<<ggrid, 256, 0, stream>>>(xb, Wqb, bq, Qb, M, HH, HH);
    gemm_bt<0><<<ggrid, 256, 0, stream>>>(xb, Wkb, bk, Kb, M, HH, HH);
    gemm_bt<1><<<ggrid, 256, 0, stream>>>(xb, Wvb, bv, Vtb, M, HH, HH);

    dim3 agrid(SS / 128, NHH, BB);   // (16, 16, 4)
    attn_kernel<<<agrid, 256, 0, stream>>>(Qb, Kb, Vtb, Ab);

    gemm_bt<2><<<ggrid, 256, 0, stream>>>(Ab, Wob, bo, out, M, HH, HH);
}

// Round 4
// 222.732 us; speedup vs baseline: 1.7054x; 1.2390x over previous
//
#include <hip/hip_runtime.h>
#include <cstdint>

// Problem constants
#define BB 4
#define SS 2048
#define HH 1024
#define NHH 16
#define HDD 64
// M = BB*SS = 8192

typedef __bf16 bf16x8 __attribute__((ext_vector_type(8)));
typedef float f32x4 __attribute__((ext_vector_type(4)));
typedef unsigned short u16x8 __attribute__((ext_vector_type(8)));

__device__ __forceinline__ unsigned short f2b(float f) {
    unsigned int u = __float_as_uint(f);
    u += 0x7fffu + ((u >> 16) & 1u);   // round-to-nearest-even
    return (unsigned short)(u >> 16);
}

__device__ __forceinline__ void gload_lds16(const void* g, void* l) {
    __builtin_amdgcn_global_load_lds(
        (const __attribute__((address_space(1))) void*)g,
        (__attribute__((address_space(3))) void*)l, 16, 0, 0);
}

// ---------------- fp32 -> bf16 conversion ----------------
__global__ void cvt_bf16(const float* __restrict__ in,
                         unsigned short* __restrict__ out, long n) {
    long i = ((long)blockIdx.x * blockDim.x + threadIdx.x) * 4;
    long stride = (long)gridDim.x * blockDim.x * 4;
    for (; i < n; i += stride) {
        float4 v = *reinterpret_cast<const float4*>(in + i);
        ushort4 o;
        o.x = f2b(v.x); o.y = f2b(v.y); o.z = f2b(v.z); o.w = f2b(v.w);
        *reinterpret_cast<ushort4*>(out + i) = o;
    }
}

// 4 weight matrices (each HH*HH), outputs contiguous at out + y*HH*HH
__global__ void cvt_w4(const float* __restrict__ w0, const float* __restrict__ w1,
                       const float* __restrict__ w2, const float* __restrict__ w3,
                       unsigned short* __restrict__ out) {
    const float* s = blockIdx.y == 0 ? w0 : blockIdx.y == 1 ? w1 : blockIdx.y == 2 ? w2 : w3;
    unsigned short* o = out + (size_t)blockIdx.y * ((size_t)HH * HH);
    long n = (long)HH * HH;
    long stride = (long)gridDim.x * blockDim.x * 4;
    for (long i = ((long)blockIdx.x * blockDim.x + threadIdx.x) * 4; i < n; i += stride) {
        float4 v = *reinterpret_cast<const float4*>(s + i);
        ushort4 w;
        w.x = f2b(v.x); w.y = f2b(v.y); w.z = f2b(v.z); w.w = f2b(v.w);
        *reinterpret_cast<ushort4*>(o + i) = w;
    }
}

// ---------------- GEMM: C[m][n] = sum_k A[m][k]*B[n][k] + bias[n] ----------------
// m97 structure: 128x128 tile, BK=32, global_load_lds width=16, linear LDS.
// MODE 0: write bf16 C row-major [M][N]
// MODE 1: write bf16 V transposed per head with key-permuted seq index
// MODE 2: write fp32 C row-major [M][N]
template<int MODE>
__global__ __launch_bounds__(256) void gemm_bt(
    const unsigned short* __restrict__ A,   // [M][K] bf16
    const unsigned short* __restrict__ Bm,  // [N][K] bf16
    const float* __restrict__ bias,         // [N]
    void* __restrict__ Cout,
    int M, int N, int K)
{
    __shared__ alignas(16) unsigned short Al[128][32];
    __shared__ alignas(16) unsigned short Bl[128][32];

    const int tid = threadIdx.x;
    const int lane = tid & 63;
    const int wid  = tid >> 6;
    const int wm = wid >> 1, wn = wid & 1;
    const int l15 = lane & 15, g = lane >> 4;
    const int row0 = blockIdx.y * 128, col0 = blockIdx.x * 128;

    f32x4 acc[4][4];
#pragma unroll
    for (int i = 0; i < 4; i++)
#pragma unroll
        for (int j = 0; j < 4; j++) acc[i][j] = (f32x4)0.0f;

    const int off0 = tid * 16;
    const int r0s = off0 >> 6, cb0 = off0 & 63;
    const int off1 = off0 + 4096;
    const int r1s = off1 >> 6, cb1 = off1 & 63;

    for (int k0 = 0; k0 < K; k0 += 32) {
        const char* gA = (const char*)(A + (size_t)row0 * K + k0);
        const char* gB = (const char*)(Bm + (size_t)col0 * K + k0);
        char* lA = (char*)&Al[0][0] + wid * 1024;
        char* lB = (char*)&Bl[0][0] + wid * 1024;
        gload_lds16(gA + (size_t)r0s * (K * 2) + cb0, lA);
        gload_lds16(gA + (size_t)r1s * (K * 2) + cb1, lA + 4096);
        gload_lds16(gB + (size_t)r0s * (K * 2) + cb0, lB);
        gload_lds16(gB + (size_t)r1s * (K * 2) + cb1, lB + 4096);
        __syncthreads();

        bf16x8 af[4], bf[4];
#pragma unroll
        for (int i = 0; i < 4; i++)
            af[i] = *reinterpret_cast<const bf16x8*>(&Al[wm * 64 + i * 16 + l15][g * 8]);
#pragma unroll
        for (int j = 0; j < 4; j++)
            bf[j] = *reinterpret_cast<const bf16x8*>(&Bl[wn * 64 + j * 16 + l15][g * 8]);
        __builtin_amdgcn_s_setprio(1);
#pragma unroll
        for (int i = 0; i < 4; i++)
#pragma unroll
            for (int j = 0; j < 4; j++)
                acc[i][j] = __builtin_amdgcn_mfma_f32_16x16x32_bf16(af[i], bf[j], acc[i][j], 0, 0, 0);
        __builtin_amdgcn_s_setprio(0);
        __syncthreads();
    }

    // epilogue
#pragma unroll
    for (int i = 0; i < 4; i++) {
#pragma unroll
        for (int j = 0; j < 4; j++) {
#pragma unroll
            for (int r = 0; r < 4; r++) {
                int row = row0 + wm * 64 + i * 16 + g * 4 + r;
                int col = col0 + wn * 64 + j * 16 + l15;
                float v = acc[i][j][r] + bias[col];
                if (MODE == 0) {
                    reinterpret_cast<unsigned short*>(Cout)[(size_t)row * N + col] = f2b(v);
                } else if (MODE == 1) {
                    int b = row >> 11;          // row / S
                    int s = row & (SS - 1);
                    int s6 = s & 63;
                    int sp6 = (s6 & 0x23) | ((s6 & 0x0C) << 1) | ((s6 & 0x10) >> 2);
                    int head = col >> 6;        // col / HD
                    int d = col & (HDD - 1);
                    size_t idx = (((size_t)b * NHH + head) * HDD + d) * SS + (s & ~63) + sp6;
                    reinterpret_cast<unsigned short*>(Cout)[idx] = f2b(v);
                } else {
                    reinterpret_cast<float*>(Cout)[(size_t)row * N + col] = v;
                }
            }
        }
    }
}

// ---------------- Flash attention (swapped QK^T, P in registers, dbuf LDS) ----------------
// Q,K: bf16 [B*S][H];  Vt: bf16 [B][NH][HD][S] key-permuted;  Oa: bf16 [B*S][H]
__global__ __launch_bounds__(256, 4) void attn_kernel(
    const unsigned short* __restrict__ Q,
    const unsigned short* __restrict__ K,
    const unsigned short* __restrict__ Vt,
    unsigned short* __restrict__ Oa)
{
    __shared__ alignas(16) unsigned short Kl[2][64][72];
    __shared__ alignas(16) unsigned short Vl[2][64][72];

    const int tid = threadIdx.x;
    const int lane = tid & 63;
    const int wid  = tid >> 6;
    const int l15 = lane & 15, g = lane >> 4;

    const int b  = blockIdx.z;
    const int h  = blockIdx.y;
    const int q0 = blockIdx.x * 128;
    const int qA = q0 + wid * 32;       // wave handles q-cols qA..+15 (A), qA+16..+31 (B)

    // Q as B-fragments, prescaled into log2 domain
    const float qs = 0.125f * 1.44269504088896f;
    const unsigned short* qpA = Q + (size_t)(b * SS + qA + l15) * HH + h * HDD + g * 8;
    const unsigned short* qpB = qpA + (size_t)16 * HH;
    u16x8 ra0 = *reinterpret_cast<const u16x8*>(qpA);
    u16x8 ra1 = *reinterpret_cast<const u16x8*>(qpA + 32);
    u16x8 rb0 = *reinterpret_cast<const u16x8*>(qpB);
    u16x8 rb1 = *reinterpret_cast<const u16x8*>(qpB + 32);
#pragma unroll
    for (int j = 0; j < 8; j++) {
        ra0[j] = f2b(__uint_as_float((unsigned)ra0[j] << 16) * qs);
        ra1[j] = f2b(__uint_as_float((unsigned)ra1[j] << 16) * qs);
        rb0[j] = f2b(__uint_as_float((unsigned)rb0[j] << 16) * qs);
        rb1[j] = f2b(__uint_as_float((unsigned)rb1[j] << 16) * qs);
    }
    const bf16x8 qa0 = __builtin_bit_cast(bf16x8, ra0);
    const bf16x8 qa1 = __builtin_bit_cast(bf16x8, ra1);
    const bf16x8 qb0 = __builtin_bit_cast(bf16x8, rb0);
    const bf16x8 qb1 = __builtin_bit_cast(bf16x8, rb1);

    u16x8 ou;
#pragma unroll
    for (int j = 0; j < 8; j++) ou[j] = 0x3F80;   // bf16 1.0
    const bf16x8 ones8 = __builtin_bit_cast(bf16x8, ou);
    const f32x4 zero4 = (f32x4)0.0f;

    f32x4 acc_a[4], acc_b[4];
#pragma unroll
    for (int dn = 0; dn < 4; dn++) { acc_a[dn] = zero4; acc_b[dn] = zero4; }
    float m_a = -INFINITY, m_b = -INFINITY, l_a = 0.f, l_b = 0.f;

    const int sr = tid >> 2;          // 0..63
    const int sc = (tid & 3) * 16;    // 0,16,32,48

    const unsigned short* gK = K  + (size_t)(b * SS + sr) * HH + h * HDD + sc;
    const unsigned short* gV = Vt + (((size_t)b * NHH + h) * HDD + sr) * SS + sc;

    int4 kr0, kr1, vr0, vr1;

    // prologue: tile 0 direct to LDS buf 0
    kr0 = *reinterpret_cast<const int4*>(gK);
    kr1 = *reinterpret_cast<const int4*>(gK + 8);
    vr0 = *reinterpret_cast<const int4*>(gV);
    vr1 = *reinterpret_cast<const int4*>(gV + 8);
    *reinterpret_cast<int4*>(&Kl[0][sr][sc])     = kr0;
    *reinterpret_cast<int4*>(&Kl[0][sr][sc + 8]) = kr1;
    *reinterpret_cast<int4*>(&Vl[0][sr][sc])     = vr0;
    *reinterpret_cast<int4*>(&Vl[0][sr][sc + 8]) = vr1;
    gK += (size_t)64 * HH;
    gV += 64;
    __syncthreads();

    const int NT = SS / 64;
    int cur = 0;

    for (int kt = 0; kt < NT; kt++) {
        if (kt + 1 < NT) {   // issue next tile's loads; land in regs across compute
            kr0 = *reinterpret_cast<const int4*>(gK);
            kr1 = *reinterpret_cast<const int4*>(gK + 8);
            vr0 = *reinterpret_cast<const int4*>(gV);
            vr1 = *reinterpret_cast<const int4*>(gV + 8);
            gK += (size_t)64 * HH;
            gV += 64;
        }

        // ---- QK^T cluster: C[key][q], K-frags read once, shared by A and B ----
        f32x4 sa[4], sb[4];
        __builtin_amdgcn_s_setprio(1);
#pragma unroll
        for (int n = 0; n < 4; n++) {
            bf16x8 kf0 = *reinterpret_cast<const bf16x8*>(&Kl[cur][n * 16 + l15][g * 8]);
            bf16x8 kf1 = *reinterpret_cast<const bf16x8*>(&Kl[cur][n * 16 + l15][32 + g * 8]);
            sa[n] = __builtin_amdgcn_mfma_f32_16x16x32_bf16(kf0, qa0, zero4, 0, 0, 0);
            sa[n] = __builtin_amdgcn_mfma_f32_16x16x32_bf16(kf1, qa1, sa[n], 0, 0, 0);
            sb[n] = __builtin_amdgcn_mfma_f32_16x16x32_bf16(kf0, qb0, zero4, 0, 0, 0);
            sb[n] = __builtin_amdgcn_mfma_f32_16x16x32_bf16(kf1, qb1, sb[n], 0, 0, 0);
        }
        __builtin_amdgcn_s_setprio(0);

        // ---- softmax A (sa dies into pa), then softmax B ----
        bf16x8 pa0, pa1, pb0, pb1;
        {
            float u0 = fmaxf(fmaxf(sa[0][0], sa[0][1]), fmaxf(sa[0][2], sa[0][3]));
            float u1 = fmaxf(fmaxf(sa[1][0], sa[1][1]), fmaxf(sa[1][2], sa[1][3]));
            float u2 = fmaxf(fmaxf(sa[2][0], sa[2][1]), fmaxf(sa[2][2], sa[2][3]));
            float u3 = fmaxf(fmaxf(sa[3][0], sa[3][1]), fmaxf(sa[3][2], sa[3][3]));
            float mt = fmaxf(fmaxf(u0, u1), fmaxf(u2, u3));
            mt = fmaxf(mt, __shfl_xor(mt, 16));
            mt = fmaxf(mt, __shfl_xor(mt, 32));
            if (!__all(mt - m_a <= 8.0f)) {
                float mnew = fmaxf(m_a, mt);
                float scl = __builtin_amdgcn_exp2f(m_a - mnew);
                m_a = mnew; l_a *= scl;
#pragma unroll
                for (int dn = 0; dn < 4; dn++)
#pragma unroll
                    for (int r = 0; r < 4; r++) acc_a[dn][r] *= scl;
            }
            float p[4][4];
#pragma unroll
            for (int n = 0; n < 4; n++)
#pragma unroll
                for (int r = 0; r < 4; r++) p[n][r] = __builtin_amdgcn_exp2f(sa[n][r] - m_a);
#pragma unroll
            for (int j = 0; j < 8; j++) {
                pa0[j] = (__bf16)p[j >> 2][j & 3];
                pa1[j] = (__bf16)p[2 + (j >> 2)][j & 3];
            }
        }
        {
            float u0 = fmaxf(fmaxf(sb[0][0], sb[0][1]), fmaxf(sb[0][2], sb[0][3]));
            float u1 = fmaxf(fmaxf(sb[1][0], sb[1][1]), fmaxf(sb[1][2], sb[1][3]));
            float u2 = fmaxf(fmaxf(sb[2][0], sb[2][1]), fmaxf(sb[2][2], sb[2][3]));
            float u3 = fmaxf(fmaxf(sb[3][0], sb[3][1]), fmaxf(sb[3][2], sb[3][3]));
            float mt = fmaxf(fmaxf(u0, u1), fmaxf(u2, u3));
            mt = fmaxf(mt, __shfl_xor(mt, 16));
            mt = fmaxf(mt, __shfl_xor(mt, 32));
            if (!__all(mt - m_b <= 8.0f)) {
                float mnew = fmaxf(m_b, mt);
                float scl = __builtin_amdgcn_exp2f(m_b - mnew);
                m_b = mnew; l_b *= scl;
#pragma unroll
                for (int dn = 0; dn < 4; dn++)
#pragma unroll
                    for (int r = 0; r < 4; r++) acc_b[dn][r] *= scl;
            }
            float p[4][4];
#pragma unroll
            for (int n = 0; n < 4; n++)
#pragma unroll
                for (int r = 0; r < 4; r++) p[n][r] = __builtin_amdgcn_exp2f(sb[n][r] - m_b);
#pragma unroll
            for (int j = 0; j < 8; j++) {
                pb0[j] = (__bf16)p[j >> 2][j & 3];
                pb1[j] = (__bf16)p[2 + (j >> 2)][j & 3];
            }
        }

        // ---- PV + l-sum cluster ----
        f32x4 la = zero4, lb = zero4;
        __builtin_amdgcn_s_setprio(1);
#pragma unroll
        for (int ks = 0; ks < 2; ks++) {
            bf16x8 pA = ks ? pa1 : pa0;
            bf16x8 pB = ks ? pb1 : pb0;
#pragma unroll
            for (int dn = 0; dn < 4; dn++) {
                bf16x8 vf = *reinterpret_cast<const bf16x8*>(&Vl[cur][dn * 16 + l15][ks * 32 + g * 8]);
                acc_a[dn] = __builtin_amdgcn_mfma_f32_16x16x32_bf16(vf, pA, acc_a[dn], 0, 0, 0);
                acc_b[dn] = __builtin_amdgcn_mfma_f32_16x16x32_bf16(vf, pB, acc_b[dn], 0, 0, 0);
            }
        }
        la = __builtin_amdgcn_mfma_f32_16x16x32_bf16(ones8, pa0, la, 0, 0, 0);
        la = __builtin_amdgcn_mfma_f32_16x16x32_bf16(ones8, pa1, la, 0, 0, 0);
        lb = __builtin_amdgcn_mfma_f32_16x16x32_bf16(ones8, pb0, lb, 0, 0, 0);
        lb = __builtin_amdgcn_mfma_f32_16x16x32_bf16(ones8, pb1, lb, 0, 0, 0);
        __builtin_amdgcn_s_setprio(0);
        l_a += la[0];
        l_b += lb[0];

        // ---- stage next tile into the other buffer; ONE barrier per tile ----
        if (kt + 1 < NT) {
            int nxt = cur ^ 1;
            *reinterpret_cast<int4*>(&Kl[nxt][sr][sc])     = kr0;
            *reinterpret_cast<int4*>(&Kl[nxt][sr][sc + 8]) = kr1;
            *reinterpret_cast<int4*>(&Vl[nxt][sr][sc])     = vr0;
            *reinterpret_cast<int4*>(&Vl[nxt][sr][sc + 8]) = vr1;
        }
        __syncthreads();
        cur ^= 1;
    }

    // normalize and write O: lane holds O[q = l15][d = dn*16 + g*4 + r]
    float inv_a = 1.0f / l_a;
    float inv_b = 1.0f / l_b;
    unsigned short* oA = Oa + (size_t)(b * SS + qA + l15) * HH + h * HDD;
    unsigned short* oB = oA + (size_t)16 * HH;
#pragma unroll
    for (int dn = 0; dn < 4; dn++) {
        ushort4 wa, wb;
        wa.x = f2b(acc_a[dn][0] * inv_a); wa.y = f2b(acc_a[dn][1] * inv_a);
        wa.z = f2b(acc_a[dn][2] * inv_a); wa.w = f2b(acc_a[dn][3] * inv_a);
        wb.x = f2b(acc_b[dn][0] * inv_b); wb.y = f2b(acc_b[dn][1] * inv_b);
        wb.z = f2b(acc_b[dn][2] * inv_b); wb.w = f2b(acc_b[dn][3] * inv_b);
        *reinterpret_cast<ushort4*>(oA + dn * 16 + g * 4) = wa;
        *reinterpret_cast<ushort4*>(oB + dn * 16 + g * 4) = wb;
    }
}

// ---------------- launcher ----------------
extern "C" void kernel_launch(void* const* d_in, const int* in_sizes, int n_in,
                              void* d_out, int out_size, void* d_ws, size_t ws_size,
                              hipStream_t stream) {
    const float* x  = (const float*)d_in[0];
    const float* Wq = (const float*)d_in[1];
    const float* bq = (const float*)d_in[2];
    const float* Wk = (const float*)d_in[3];
    const float* bk = (const float*)d_in[4];
    const float* Wv = (const float*)d_in[5];
    const float* bv = (const float*)d_in[6];
    const float* Wo = (const float*)d_in[7];
    const float* bo = (const float*)d_in[8];
    float* out = (float*)d_out;

    const int M = BB * SS;   // 8192
    const long nx = (long)M * HH;       // 8388608

    unsigned char* ws = (unsigned char*)d_ws;
    unsigned short* xb  = (unsigned short*)(ws);
    unsigned short* Wqb = (unsigned short*)(ws + 16777216);
    unsigned short* Wkb = (unsigned short*)(ws + 16777216 + 2097152);
    unsigned short* Wvb = (unsigned short*)(ws + 16777216 + 2 * 2097152);
    unsigned short* Wob = (unsigned short*)(ws + 16777216 + 3 * 2097152);
    unsigned short* Qb  = (unsigned short*)(ws + 16777216 + 4 * 2097152);
    unsigned short* Kb  = (unsigned short*)(ws + 2 * 16777216 + 4 * 2097152);
    unsigned short* Vtb = (unsigned short*)(ws + 3 * 16777216 + 4 * 2097152);
    unsigned short* Ab  = (unsigned short*)(ws + 4 * 16777216 + 4 * 2097152);

    // fp32 -> bf16
    cvt_bf16<<<4096, 256, 0, stream>>>(x, xb, nx);
    cvt_w4<<<dim3(256, 4), 256, 0, stream>>>(Wq, Wk, Wv, Wo, Wqb);

    dim3 ggrid(HH / 128, M / 128);   // (8, 64)
    gemm_bt<0><<<ggrid, 256, 0, stream>>>(xb, Wqb, bq, Qb, M, HH, HH);
    gemm_bt<0><<<ggrid, 256, 0, stream>>>(xb, Wkb, bk, Kb, M, HH, HH);
    gemm_bt<1><<<ggrid, 256, 0, stream>>>(xb, Wvb, bv, Vtb, M, HH, HH);

    dim3 agrid(SS / 128, NHH, BB);   // (16, 16, 4)
    attn_kernel<<<agrid, 256, 0, stream>>>(Qb, Kb, Vtb, Ab);

    gemm_bt<2><<<ggrid, 256, 0, stream>>>(Ab, Wob, bo, out, M, HH, HH);
}